// Round 17
// baseline (370.442 us; speedup 1.0000x reference)
//
#include <hip/hip_runtime.h>

#define NPOS 16384   // D*H*W
#define KSPLIT 8
#define KEYS_PER_BLK (NPOS / KSPLIT)   // 2048
#define CHUNK 512
#define LOG2E 1.4426950408889634f

typedef short bf16x8 __attribute__((ext_vector_type(8)));
typedef unsigned short u16x8 __attribute__((ext_vector_type(8)));
typedef float floatx16 __attribute__((ext_vector_type(16)));
typedef float floatx2 __attribute__((ext_vector_type(2)));

static __device__ __forceinline__ unsigned short f2bf(float f) {
    return (unsigned short)(__builtin_bit_cast(unsigned int, f) >> 16);
}
static __device__ __forceinline__ float bf2f(unsigned short h) {
    return __builtin_bit_cast(float, (unsigned int)h << 16);
}

#if __has_builtin(__builtin_amdgcn_exp2f)
static __device__ __forceinline__ float exp2_fast(float x) {
    return __builtin_amdgcn_exp2f(x);
}
#else
static __device__ __forceinline__ float exp2_fast(float x) {
    float r;
    asm("v_exp_f32 %0, %1" : "=v"(r) : "v"(x));
    return r;
}
#endif

// pack hi16(a_even)|hi16(a_odd) -> one VGPR with 2 bf16 (even in low half)
static __device__ __forceinline__ unsigned int pk_bf16(float e_even, float e_odd) {
    return __builtin_amdgcn_perm(__builtin_bit_cast(unsigned int, e_odd),
                                 __builtin_bit_cast(unsigned int, e_even),
                                 0x07060302u);
}

// sigma: swap middle two 4-key nibbles per 16 keys (involution)
static __device__ __forceinline__ int sigma(int n) {
    const int w12 = n & 12;
    return (w12 == 4 || w12 == 8) ? (n ^ 12) : n;
}

// ---------------------------------------------------------------------------
// Projection (unchanged). Grid (64, 10), block 256.
// g==0: q (prescaled log2e) -> qb16 [n][8] bf16. g==1: k -> kb16.
// g>=2: v channels (g-2)*8..+7 -> vbg16 bf16, sigma-space group-major:
//   ushort index = (sigma(n)>>3)*512 + ch*8 + (sigma(n)&7)
// ---------------------------------------------------------------------------
__global__ __launch_bounds__(256) void proj_kernel(
    const float* __restrict__ x,
    const float* __restrict__ wq, const float* __restrict__ bq,
    const float* __restrict__ wk, const float* __restrict__ bk,
    const float* __restrict__ wv, const float* __restrict__ bv,
    unsigned short* __restrict__ qb16, unsigned short* __restrict__ kb16,
    unsigned short* __restrict__ vbg16)
{
    const int t = threadIdx.x;
    const int n = blockIdx.x * 256 + t;
    const int g = blockIdx.y;

    const float* w;
    const float* b;
    if (g == 0)      { w = wq; b = bq; }
    else if (g == 1) { w = wk; b = bk; }
    else             { w = wv + (g - 2) * 8 * 64; b = bv + (g - 2) * 8; }

    float acc[8];
#pragma unroll
    for (int oo = 0; oo < 8; ++oo) acc[oo] = b[oo];
#pragma unroll 16
    for (int c = 0; c < 64; ++c) {
        const float xv = x[c * NPOS + n];
#pragma unroll
        for (int oo = 0; oo < 8; ++oo)
            acc[oo] = fmaf(w[oo * 64 + c], xv, acc[oo]);
    }

    if (g == 0) {
        u16x8 qp;
#pragma unroll
        for (int j = 0; j < 8; ++j) qp[j] = f2bf(acc[j] * LOG2E);
        ((uint4*)qb16)[n] = __builtin_bit_cast(uint4, qp);
    } else if (g == 1) {
        u16x8 kp;
#pragma unroll
        for (int j = 0; j < 8; ++j) kp[j] = f2bf(acc[j]);
        ((uint4*)kb16)[n] = __builtin_bit_cast(uint4, kp);
    } else {
        const int o0 = (g - 2) * 8;
        const int np = sigma(n);
        const size_t base = (size_t)(np >> 3) * 512 + (np & 7);
#pragma unroll
        for (int oo = 0; oo < 8; ++oo)
            vbg16[base + (size_t)(o0 + oo) * 8] = f2bf(acc[oo]);
    }
}

// process one 32x32 score tile: exp2 + den + pack, paired to keep only
// 2 e-floats live (spill fix vs R16's e[16] arrays)
static __device__ __forceinline__ void tile_post(
    const floatx16& s, floatx2& dacc, unsigned int (&P)[8])
{
#pragma unroll
    for (int p = 0; p < 8; ++p) {
        const float e0 = exp2_fast(s[2 * p]);
        const float e1 = exp2_fast(s[2 * p + 1]);
        dacc += (floatx2){e0, e1};
        P[p] = pk_bf16(e0, e1);
    }
}

// ---------------------------------------------------------------------------
// Attention partials + FUSED finalize. Grid = 128 qblocks(128q) x 8 kq =
// 1024 blocks (exact 4-blocks/CU co-residency), 256 threads.
// Wave (qpair, khalf): TWO 32-query tiles x 256-key half of each chunk;
// both tiles share K and V fragments. Per-tile algebra unchanged (see R15).
// After the epilogue stores, blocks release (threadfence) and bump a
// per-qblk counter; the 8th finisher runs the finalize for its 4 query
// tiles inline (split-k semaphore: overlaps finalize with the attn tail
// and deletes the 3rd dispatch + its full-device drain).
// ---------------------------------------------------------------------------
__global__ __launch_bounds__(256, 4) void attn_kernel(
    const uint4* __restrict__ qb4,   // [n] 8 bf16 (prescaled log2e)
    const uint4* __restrict__ kb4,   // [n] 8 bf16, natural order
    const uint4* __restrict__ vbg4,  // [key/8][64 ch] uint4 bf16, sigma space
    unsigned short* __restrict__ nump,  // [8][512][64][32] bf16
    float* __restrict__ denp,           // [8][NPOS] fp32
    unsigned int* __restrict__ cnt,     // [128] zeroed
    const float* __restrict__ x,
    const float* __restrict__ gamma,
    float* __restrict__ out)
{
    __shared__ __align__(16) char smem[16896];
    __shared__ int sflag;
    uint4* k_lds = (uint4*)smem;   // 512 keys (8 KB); epilogue aliases

    const int t     = threadIdx.x;
    const int wave  = t >> 6;
    const int lane  = t & 63;
    const int m     = lane & 31;
    const int half  = lane >> 5;
    const int qpair = wave >> 1;
    const int khalf = wave & 1;

    const int qblk = blockIdx.x >> 3;
    const int kq   = blockIdx.x & 7;
    const int i0   = qblk * 128;
    const int jb   = kq * KEYS_PER_BLK;
    const int qt0  = (i0 >> 5) + qpair * 2;   // this wave's tiles qt0, qt0+1

    const uint4 zero4 = make_uint4(0, 0, 0, 0);
    const uint4 qLo4 = (half == 0) ? qb4[i0 + qpair * 64 + m]      : zero4;
    const uint4 qHi4 = (half == 0) ? qb4[i0 + qpair * 64 + 32 + m] : zero4;
    const bf16x8 bqLo = __builtin_bit_cast(bf16x8, qLo4);
    const bf16x8 bqHi = __builtin_bit_cast(bf16x8, qHi4);

    floatx16 accLoA = {}, accLoB = {};   // tile Lo, ch 0..31 / 32..63
    floatx16 accHiA = {}, accHiB = {};   // tile Hi
    floatx2  dLo = {0.f, 0.f}, dHi = {0.f, 0.f};

#pragma unroll 1
    for (int c4 = 0; c4 < 4; ++c4) {
        const int j0 = jb + c4 * CHUNK;
        __syncthreads();
        k_lds[t]       = kb4[j0 + t];
        k_lds[256 + t] = kb4[j0 + 256 + t];
        __syncthreads();

        const int kwb = khalf * 256;   // wave's 256-key window in chunk
#pragma unroll 1
        for (int st = 0; st < 8; ++st) {
            const int kb_ = kwb + st * 32;
            const bf16x8 ak = __builtin_bit_cast(bf16x8, k_lds[kb_ + m]);

            // V fragments: shared by both tiles
            const int g8t = (j0 + kb_) >> 3;
            bf16x8 vf0[2], vf1[2];
#pragma unroll
            for (int f = 0; f < 2; ++f) {
                const int g8 = g8t + f * 2 + half;
                vf0[f] = __builtin_bit_cast(bf16x8, vbg4[(size_t)g8 * 64 + m]);
                vf1[f] = __builtin_bit_cast(bf16x8,
                                            vbg4[(size_t)g8 * 64 + 32 + m]);
            }

            // ---- tile Lo ----
            {
                const floatx16 s = __builtin_amdgcn_mfma_f32_32x32x16_bf16(
                    ak, bqLo, (floatx16){}, 0, 0, 0);
                unsigned int P[8];
                tile_post(s, dLo, P);
#pragma unroll
                for (int f = 0; f < 2; ++f) {
                    uint4 afu;
                    afu.x = P[4 * f + 0];
                    afu.y = P[4 * f + 1];
                    afu.z = P[4 * f + 2];
                    afu.w = P[4 * f + 3];
                    const bf16x8 af = __builtin_bit_cast(bf16x8, afu);
                    accLoA = __builtin_amdgcn_mfma_f32_32x32x16_bf16(
                        af, vf0[f], accLoA, 0, 0, 0);
                    accLoB = __builtin_amdgcn_mfma_f32_32x32x16_bf16(
                        af, vf1[f], accLoB, 0, 0, 0);
                }
            }
            // ---- tile Hi ----
            {
                const floatx16 s = __builtin_amdgcn_mfma_f32_32x32x16_bf16(
                    ak, bqHi, (floatx16){}, 0, 0, 0);
                unsigned int P[8];
                tile_post(s, dHi, P);
#pragma unroll
                for (int f = 0; f < 2; ++f) {
                    uint4 afu;
                    afu.x = P[4 * f + 0];
                    afu.y = P[4 * f + 1];
                    afu.z = P[4 * f + 2];
                    afu.w = P[4 * f + 3];
                    const bf16x8 af = __builtin_bit_cast(bf16x8, afu);
                    accHiA = __builtin_amdgcn_mfma_f32_32x32x16_bf16(
                        af, vf0[f], accHiA, 0, 0, 0);
                    accHiB = __builtin_amdgcn_mfma_f32_32x32x16_bf16(
                        af, vf1[f], accHiB, 0, 0, 0);
                }
            }
        }
    }

    // per-query den (each tile): fold pair, combine khalves
    const float dlLo = dLo[0] + dLo[1];
    const float dwLo = dlLo + __shfl_xor(dlLo, 32);
    const float dlHi = dHi[0] + dHi[1];
    const float dwHi = dlHi + __shfl_xor(dlHi, 32);

    // khalf-pair merge via LDS (aliases k_lds; safe after barrier)
    __syncthreads();
    float*          xden = (float*)smem;                    // 128 f32
    unsigned short* xacc = (unsigned short*)(smem + 512);   // [4][64][32]
    if (khalf == 1) {
        if (half == 0) {
            xden[(qpair * 2 + 0) * 32 + m] = dwLo;
            xden[(qpair * 2 + 1) * 32 + m] = dwHi;
        }
#pragma unroll
        for (int tile = 0; tile < 2; ++tile) {
            const floatx16* aA = tile ? &accHiA : &accLoA;
            const floatx16* aB = tile ? &accHiB : &accLoB;
            u16x8 a0, a1, a2, a3;
#pragma unroll
            for (int j = 0; j < 8; ++j) {
                a0[j] = f2bf((*aA)[j]);
                a1[j] = f2bf((*aA)[8 + j]);
                a2[j] = f2bf((*aB)[j]);
                a3[j] = f2bf((*aB)[8 + j]);
            }
            uint4* dst = (uint4*)(xacc + ((qpair * 2 + tile) * 64 + lane) * 32);
            dst[0] = __builtin_bit_cast(uint4, a0);
            dst[1] = __builtin_bit_cast(uint4, a1);
            dst[2] = __builtin_bit_cast(uint4, a2);
            dst[3] = __builtin_bit_cast(uint4, a3);
        }
    }
    __syncthreads();
    if (khalf == 0) {
#pragma unroll
        for (int tile = 0; tile < 2; ++tile) {
            const floatx16* aA = tile ? &accHiA : &accLoA;
            const floatx16* aB = tile ? &accHiB : &accLoB;
            const uint4* src =
                (const uint4*)(xacc + ((qpair * 2 + tile) * 64 + lane) * 32);
            const u16x8 b0 = __builtin_bit_cast(u16x8, src[0]);
            const u16x8 b1 = __builtin_bit_cast(u16x8, src[1]);
            const u16x8 b2 = __builtin_bit_cast(u16x8, src[2]);
            const u16x8 b3 = __builtin_bit_cast(u16x8, src[3]);
            u16x8 o0, o1, o2, o3;
#pragma unroll
            for (int j = 0; j < 8; ++j) {
                o0[j] = f2bf((*aA)[j]      + bf2f(b0[j]));
                o1[j] = f2bf((*aA)[8 + j]  + bf2f(b1[j]));
                o2[j] = f2bf((*aB)[j]      + bf2f(b2[j]));
                o3[j] = f2bf((*aB)[8 + j]  + bf2f(b3[j]));
            }
            const size_t base =
                (((size_t)kq * 512 + qt0 + tile) * 64 + lane) * 32;
            uint4* gdst = (uint4*)(nump + base);
            gdst[0] = __builtin_bit_cast(uint4, o0);
            gdst[1] = __builtin_bit_cast(uint4, o1);
            gdst[2] = __builtin_bit_cast(uint4, o2);
            gdst[3] = __builtin_bit_cast(uint4, o3);
        }
        if (half == 0) {
            denp[(size_t)kq * NPOS + (qt0 + 0) * 32 + m] =
                dwLo + xden[(qpair * 2 + 0) * 32 + m];
            denp[(size_t)kq * NPOS + (qt0 + 1) * 32 + m] =
                dwHi + xden[(qpair * 2 + 1) * 32 + m];
        }
    }

    // ---- split-k semaphore: release stores, bump counter ----
    __threadfence();          // every wave: drain + make stores visible
    __syncthreads();
    if (t == 0) sflag = (atomicAdd(&cnt[qblk], 1u) == 7u);
    __syncthreads();
    if (!sflag) return;

    // ---- finisher: finalize this qblk's 4 query tiles ----
    __threadfence();          // acquire side
    float* dsum = (float*)smem;          // 32 f32
    float* ot   = (float*)(smem + 128);  // [32][66]
    const float g    = gamma[0];
    const int   lane4 = t >> 2;
    const int   u     = t & 3;

#pragma unroll 1
    for (int tile = 0; tile < 4; ++tile) {
        const int b4 = qblk * 4 + tile;
        const int n0 = b4 * 32;

        __syncthreads();
        if (t < 32) dsum[t] = 0.f;
        __syncthreads();
        atomicAdd(&dsum[t & 31],
                  denp[(size_t)(t >> 5) * NPOS + n0 + (t & 31)]);

        float ns[8];
#pragma unroll
        for (int j = 0; j < 8; ++j) ns[j] = 0.f;
#pragma unroll
        for (int kk = 0; kk < 8; ++kk) {
            const size_t base =
                (((size_t)kk * 512 + b4) * 64 + lane4) * 32 + u * 8;
            const u16x8 h =
                __builtin_bit_cast(u16x8, *(const uint4*)(nump + base));
#pragma unroll
            for (int j = 0; j < 8; ++j) ns[j] += bf2f(h[j]);
        }

        const int clow = lane4 & 31;
        const int hf   = lane4 >> 5;
#pragma unroll
        for (int j = 0; j < 8; ++j) {
            const int off = u * 8 + j;
            const int r   = off & 15;
            const int row = (r & 3) + 8 * (r >> 2) + 4 * hf;
            const int c   = (off >> 4) * 32 + clow;
            ot[row * 66 + c] = ns[j];
        }
        __syncthreads();

        const int c2 = t >> 2;       // channel 0..63
        const int nq = t & 3;        // n-octet 0..3
#pragma unroll
        for (int j = 0; j < 8; ++j) {
            const int row = nq * 8 + j;
            const size_t gi = (size_t)c2 * NPOS + n0 + row;
            out[gi] = fmaf(g, ot[row * 66 + c2] *
                                  __builtin_amdgcn_rcpf(dsum[row]), x[gi]);
        }
    }
}

// ---------------------------------------------------------------------------
extern "C" void kernel_launch(void* const* d_in, const int* in_sizes, int n_in,
                              void* d_out, int out_size, void* d_ws, size_t ws_size,
                              hipStream_t stream)
{
    (void)in_sizes; (void)n_in; (void)out_size; (void)ws_size;

    const float* x     = (const float*)d_in[0];
    const float* wq    = (const float*)d_in[1];
    const float* bq    = (const float*)d_in[2];
    const float* wk    = (const float*)d_in[3];
    const float* bk    = (const float*)d_in[4];
    const float* wv    = (const float*)d_in[5];
    const float* bv    = (const float*)d_in[6];
    const float* gamma = (const float*)d_in[7];
    float* out = (float*)d_out;

    char* ws = (char*)d_ws;
    unsigned short* qb16  = (unsigned short*)(ws);              // 256 KB
    unsigned short* kb16  = (unsigned short*)(ws + 262144);     // 256 KB
    unsigned short* vbg16 = (unsigned short*)(ws + 524288);     // 2 MB
    unsigned short* nump  = (unsigned short*)(ws + 2621440);    // 16 MB bf16
    float*          denp  = (float*)(ws + 19398656);            // 512 KB
    unsigned int*   cnt   = (unsigned int*)(ws + 19922944);     // 512 B

    hipMemsetAsync(cnt, 0, 128 * sizeof(unsigned int), stream);

    proj_kernel<<<dim3(NPOS / 256, 10), 256, 0, stream>>>(
        x, wq, bq, wk, bk, wv, bv, qb16, kb16, vbg16);
    attn_kernel<<<(NPOS / 128) * KSPLIT, 256, 0, stream>>>(
        (const uint4*)qb16, (const uint4*)kb16, (const uint4*)vbg16,
        nump, denp, cnt, x, gamma, out);
}